// Round 5
// baseline (721.723 us; speedup 1.0000x reference)
//
#include <hip/hip_runtime.h>

// GAT 2-layer on gfx950. Round 5: inputs are float32 (reference dtype) — prior
// rounds read them as bf16 -> inf -> sanitizer zeroed everything. This build
// auto-detects dtype on-device (probe of x's low-16-bit distribution), converts
// all float inputs to canonical bf16 in scratch, runs the MFMA pipeline, and
// stores the output as f32 or bf16 per the detected flag. Scratch (160 MB)
// allocated once at dlopen (capture-safe).

typedef __bf16 bf16x8 __attribute__((ext_vector_type(8)));
typedef float f32x4 __attribute__((ext_vector_type(4)));

static void* g_scratch = nullptr;
#define SCRATCH_BYTES ((size_t)160 * 1024 * 1024)

__attribute__((constructor)) static void alloc_scratch_at_load() {
    if (hipMalloc(&g_scratch, SCRATCH_BYTES) != hipSuccess) g_scratch = nullptr;
}

__device__ __forceinline__ float bf2f(unsigned short u) {
    union { unsigned int i; float f; } v;
    v.i = ((unsigned int)u) << 16;
    return v.f;
}
__device__ __forceinline__ unsigned short f2bf(float f) {
    union { float f; unsigned int i; } v;
    v.f = f;
    unsigned int x = v.i;
    return (unsigned short)((x + 0x7fffu + ((x >> 16) & 1u)) >> 16); // RNE
}
__device__ __forceinline__ float fin(float v) {
    return (v == v && fabsf(v) <= 3.0e38f) ? v : 0.f; // NaN/inf -> 0
}

// ---------------- dtype probe ----------------
// f32 N(0,1) data: low 16 bits of each word are uniform mantissa bits ->
// ~3% decode to bf16 with |v| in [2^-7, 2). Packed bf16 data: low half is a
// real bf16 of N(0,1) -> ~95% in range. flag=1 means f32 inputs.

__global__ void probe_kernel(const unsigned int* __restrict__ xw, int* __restrict__ flag) {
    int lane = threadIdx.x; // 64 threads
    int cnt = 0;
    for (int i = lane; i < 1024; i += 64) {
        float v = bf2f((unsigned short)(xw[i] & 0xffffu));
        float a = fabsf(v);
        if (a >= 0.0078125f && a < 2.0f) cnt++;
    }
    #pragma unroll
    for (int off = 32; off; off >>= 1) cnt += __shfl_xor(cnt, off);
    if (lane == 0) *flag = (cnt < 512) ? 1 : 0;
}

// canonicalize: any float input -> bf16 copy in scratch
__global__ __launch_bounds__(256) void cvt_kernel(const void* __restrict__ src,
                                                  unsigned short* __restrict__ dst, int n,
                                                  const int* __restrict__ flag) {
    int i = blockIdx.x * 256 + threadIdx.x;
    if (i >= n) return;
    if (*flag) dst[i] = f2bf(((const float*)src)[i]);
    else       dst[i] = ((const unsigned short*)src)[i];
}

// ---------------- diagnostic fill ----------------

__global__ __launch_bounds__(256) void fill_kernel(unsigned short* __restrict__ out, int n,
                                                   float val) {
    int i = blockIdx.x * 256 + threadIdx.x;
    if (i < n) out[i] = f2bf(val);
}

// ---------------- CSR build ----------------

__global__ __launch_bounds__(256) void deg_kernel(const int* __restrict__ ei, int E, int N,
                                                  int* __restrict__ deg) {
    int i = blockIdx.x * 256 + threadIdx.x;
    int total = E + N;
    if (i < total) {
        int dst = (i < E) ? ei[E + i] : (i - E); // edge_index[1] row, then self-loops
        if ((unsigned)dst < (unsigned)N) atomicAdd(&deg[dst], 1);
    }
}

__global__ __launch_bounds__(1024) void scan_kernel(const int* __restrict__ deg,
                                                    int* __restrict__ rowptr,
                                                    int* __restrict__ cursor, int n) {
    __shared__ int sh[1024];
    __shared__ int carry_s;
    int tid = threadIdx.x;
    if (tid == 0) carry_s = 0;
    __syncthreads();
    for (int base = 0; base < n; base += 1024) {
        int i = base + tid;
        int v = (i < n) ? deg[i] : 0;
        sh[tid] = v;
        __syncthreads();
        #pragma unroll
        for (int off = 1; off < 1024; off <<= 1) {
            int t = (tid >= off) ? sh[tid - off] : 0;
            __syncthreads();
            sh[tid] += t;
            __syncthreads();
        }
        int incl = sh[tid];
        int excl = incl - v;
        int carry = carry_s;
        if (i < n) {
            rowptr[i] = carry + excl;
            cursor[i] = carry + excl;
        }
        int chunk_total = sh[1023];
        __syncthreads();
        if (tid == 0) carry_s = carry + chunk_total;
        __syncthreads();
    }
    if (tid == 0) rowptr[n] = carry_s;
}

__global__ __launch_bounds__(256) void scatter_kernel(const int* __restrict__ ei, int E, int N,
                                                      int* __restrict__ cursor,
                                                      int* __restrict__ csr) {
    int i = blockIdx.x * 256 + threadIdx.x;
    int total = E + N;
    if (i < total) {
        int s, d;
        if (i < E) { s = ei[i]; d = ei[E + i]; }
        else       { s = i - E; d = i - E; }
        if ((unsigned)d >= (unsigned)N) return;
        int pos = atomicAdd(&cursor[d], 1);
        if ((unsigned)pos < (unsigned)total) csr[pos] = s;
    }
}

// ---------------- GEMM: C[M,Nc] = A[M,K] * B[Nc,K]^T, bf16 in/out ----------------

template <int K, int NT>
__global__ __launch_bounds__(256) void gemm_nt_kernel(const unsigned short* __restrict__ A,
                                                      const unsigned short* __restrict__ B,
                                                      unsigned short* __restrict__ C, int M) {
    int wid = blockIdx.x * 4 + (threadIdx.x >> 6);
    int lane = threadIdx.x & 63;
    int row0 = wid * 16;
    if (row0 >= M) return;
    const int Nc = NT * 16;
    int r = lane & 15;
    int kq = lane >> 4;

    f32x4 acc[NT];
    #pragma unroll
    for (int t = 0; t < NT; ++t) acc[t] = (f32x4){0.f, 0.f, 0.f, 0.f};

    const unsigned short* Arow = A + (size_t)(row0 + r) * K + kq * 8;
    for (int k0 = 0; k0 < K; k0 += 32) {
        bf16x8 a = *reinterpret_cast<const bf16x8*>(Arow + k0);
        #pragma unroll
        for (int t = 0; t < NT; ++t) {
            const unsigned short* Bp = B + (size_t)(t * 16 + r) * K + k0 + kq * 8;
            bf16x8 b = *reinterpret_cast<const bf16x8*>(Bp);
            acc[t] = __builtin_amdgcn_mfma_f32_16x16x32_bf16(a, b, acc[t], 0, 0, 0);
        }
    }
    #pragma unroll
    for (int t = 0; t < NT; ++t) {
        #pragma unroll
        for (int q = 0; q < 4; ++q) {
            int row = row0 + kq * 4 + q;
            int col = t * 16 + r;
            C[(size_t)row * Nc + col] = f2bf(fin(acc[t][q]));
        }
    }
}

// ---------------- per-node attention scores ----------------

template <int CPL> // channels per lane; DOUT = 64*CPL
__global__ __launch_bounds__(256) void escore_kernel(const unsigned short* __restrict__ h,
                                                     const unsigned short* __restrict__ a_src,
                                                     const unsigned short* __restrict__ a_dst,
                                                     float* __restrict__ es,
                                                     float* __restrict__ ed, int n) {
    int w = blockIdx.x * 4 + (threadIdx.x >> 6);
    if (w >= n) return;
    int lane = threadIdx.x & 63;
    const int DOUT = CPL * 64;
    float s1 = 0.f, s2 = 0.f;
    #pragma unroll
    for (int i = 0; i < CPL; ++i) {
        float hv = bf2f(h[(size_t)w * DOUT + lane * CPL + i]);
        s1 += hv * bf2f(a_src[lane * CPL + i]);
        s2 += hv * bf2f(a_dst[lane * CPL + i]);
    }
    #pragma unroll
    for (int off = 32; off; off >>= 1) {
        s1 += __shfl_xor(s1, off);
        s2 += __shfl_xor(s2, off);
    }
    if (lane == 0) { es[w] = fin(s1); ed[w] = fin(s2); }
}

// ---------------- per-dst softmax + gather aggregation ----------------
// DUAL=true: store f32 or bf16 per *flagp (output dtype == input dtype).

template <int CPL, bool RELU, bool DUAL>
__global__ __launch_bounds__(256) void aggregate_kernel(const unsigned short* __restrict__ h,
                                                        const float* __restrict__ es,
                                                        const float* __restrict__ ed,
                                                        const int* __restrict__ rowptr,
                                                        const int* __restrict__ csr,
                                                        const unsigned short* __restrict__ bias,
                                                        void* __restrict__ out,
                                                        int n, int ET,
                                                        const int* __restrict__ flagp) {
    int w = blockIdx.x * 4 + (threadIdx.x >> 6); // one wave per dst node
    if (w >= n) return;
    int lane = threadIdx.x & 63;
    const int DOUT = CPL * 64;
    int f32out = DUAL ? flagp[0] : 0;
    int start = rowptr[w], end = rowptr[w + 1];
    start = max(0, min(start, ET));
    end = max(start, min(end, ET));
    float edv = ed[w];

    float m = -1e30f;
    for (int j = start + lane; j < end; j += 64) {
        int s = csr[j];
        s = ((unsigned)s < (unsigned)n) ? s : 0;
        float v = es[s] + edv;
        v = (v > 0.f) ? v : 0.2f * v;
        m = fmaxf(m, v);
    }
    #pragma unroll
    for (int off = 32; off; off >>= 1) m = fmaxf(m, __shfl_xor(m, off));
    if (!(m > -1e29f)) m = 0.f;

    float ssum = 0.f;
    float acc[CPL];
    #pragma unroll
    for (int i = 0; i < CPL; ++i) acc[i] = 0.f;

    for (int base = start; base < end; base += 64) {
        int j = base + lane;
        float p = 0.f;
        int sidx = 0;
        if (j < end) {
            int s = csr[j];
            sidx = ((unsigned)s < (unsigned)n) ? s : 0;
            float v = es[sidx] + edv;
            v = (v > 0.f) ? v : 0.2f * v;
            p = __expf(v - m);
        }
        ssum += p;
        int cnt = min(64, end - base);
        for (int jj = 0; jj < cnt; ++jj) {
            float pj = __shfl(p, jj);
            int sj = __shfl(sidx, jj);
            const unsigned short* hp = h + (size_t)sj * DOUT + lane * CPL;
            if (CPL == 4) {
                uint2 u = *reinterpret_cast<const uint2*>(hp);
                acc[0] += pj * bf2f((unsigned short)(u.x & 0xffff));
                acc[1] += pj * bf2f((unsigned short)(u.x >> 16));
                acc[2] += pj * bf2f((unsigned short)(u.y & 0xffff));
                acc[3] += pj * bf2f((unsigned short)(u.y >> 16));
            } else {
                unsigned int u = *reinterpret_cast<const unsigned int*>(hp);
                acc[0] += pj * bf2f((unsigned short)(u & 0xffff));
                acc[1] += pj * bf2f((unsigned short)(u >> 16));
            }
        }
    }
    #pragma unroll
    for (int off = 32; off; off >>= 1) ssum += __shfl_xor(ssum, off);
    float inv = 1.f / fmaxf(ssum, 1e-20f);
    #pragma unroll
    for (int i = 0; i < CPL; ++i) {
        float o = acc[i] * inv + bf2f(bias[lane * CPL + i]);
        if (RELU) o = fmaxf(o, 0.f);
        o = fin(o);
        size_t idx = (size_t)w * DOUT + lane * CPL + i;
        if (DUAL && f32out) ((float*)out)[idx] = o;
        else                ((unsigned short*)out)[idx] = f2bf(o);
    }
}

// ---------------- launch ----------------

extern "C" void kernel_launch(void* const* d_in, const int* in_sizes, int n_in,
                              void* d_out, int out_size, void* d_ws, size_t ws_size,
                              hipStream_t stream) {
    int gOut = (out_size + 255) / 256;
    if (n_in != 11) {
        fill_kernel<<<gOut, 256, 0, stream>>>((unsigned short*)d_out, out_size, 999.f);
        return;
    }

    const int N = in_sizes[0] / 512; // 50000
    const int E = in_sizes[1] / 2;   // 800000
    const int ET = E + N;

    const int NX  = in_sizes[0];   // N*512
    const int NW1 = in_sizes[3];   // 256*512
    const int NA  = in_sizes[4];   // 256
    const int NB1 = in_sizes[6];   // 256
    const int NW2 = in_sizes[7];   // 128*256
    const int NA2 = in_sizes[8];   // 128
    const int NB2 = in_sizes[10];  // 128

    size_t off = 0;
    auto reserve = [&](size_t bytes) {
        size_t o = off;
        off = (off + bytes + 255) & ~(size_t)255;
        return o;
    };
    size_t o_flag   = reserve(256);
    size_t o_es     = reserve((size_t)N * 4);
    size_t o_ed     = reserve((size_t)N * 4);
    size_t o_deg    = reserve((size_t)N * 4);
    size_t o_rowptr = reserve((size_t)(N + 1) * 4);
    size_t o_cursor = reserve((size_t)N * 4);
    size_t o_csr    = reserve((size_t)ET * 4);
    size_t o_h1     = reserve((size_t)N * 256 * 2);
    size_t o_out1   = reserve((size_t)N * 256 * 2);
    size_t o_xc     = reserve((size_t)NX * 2);
    size_t o_w1c    = reserve((size_t)NW1 * 2);
    size_t o_a1s    = reserve((size_t)NA * 2);
    size_t o_a1d    = reserve((size_t)NA * 2);
    size_t o_b1c    = reserve((size_t)NB1 * 2);
    size_t o_w2c    = reserve((size_t)NW2 * 2);
    size_t o_a2s    = reserve((size_t)NA2 * 2);
    size_t o_a2d    = reserve((size_t)NA2 * 2);
    size_t o_b2c    = reserve((size_t)NB2 * 2);
    size_t need = off;

    char* base = nullptr;
    if (ws_size >= need) base = (char*)d_ws;
    else if (g_scratch && SCRATCH_BYTES >= need) base = (char*)g_scratch;
    if (!base) {
        fill_kernel<<<gOut, 256, 0, stream>>>((unsigned short*)d_out, out_size,
                                              100.f + (float)(ws_size >> 20));
        return;
    }

    int*   flag    = (int*)(base + o_flag);
    float* es      = (float*)(base + o_es);
    float* ed      = (float*)(base + o_ed);
    int*   deg     = (int*)(base + o_deg);
    int*   rowptr  = (int*)(base + o_rowptr);
    int*   cursor  = (int*)(base + o_cursor);
    int*   csr     = (int*)(base + o_csr);
    unsigned short* h1   = (unsigned short*)(base + o_h1);
    unsigned short* out1 = (unsigned short*)(base + o_out1);
    unsigned short* xc   = (unsigned short*)(base + o_xc);
    unsigned short* w1c  = (unsigned short*)(base + o_w1c);
    unsigned short* a1sc = (unsigned short*)(base + o_a1s);
    unsigned short* a1dc = (unsigned short*)(base + o_a1d);
    unsigned short* b1c  = (unsigned short*)(base + o_b1c);
    unsigned short* w2c  = (unsigned short*)(base + o_w2c);
    unsigned short* a2sc = (unsigned short*)(base + o_a2s);
    unsigned short* a2dc = (unsigned short*)(base + o_a2d);
    unsigned short* b2c  = (unsigned short*)(base + o_b2c);

    const int* ei = (const int*)d_in[1];

    // dtype probe + canonicalize all float inputs to bf16
    probe_kernel<<<1, 64, 0, stream>>>((const unsigned int*)d_in[0], flag);
    auto cvt = [&](const void* src, unsigned short* dst, int n) {
        cvt_kernel<<<(n + 255) / 256, 256, 0, stream>>>(src, dst, n, flag);
    };
    cvt(d_in[0], xc, NX);
    cvt(d_in[3], w1c, NW1);
    cvt(d_in[4], a1sc, NA);
    cvt(d_in[5], a1dc, NA);
    cvt(d_in[6], b1c, NB1);
    cvt(d_in[7], w2c, NW2);
    cvt(d_in[8], a2sc, NA2);
    cvt(d_in[9], a2dc, NA2);
    cvt(d_in[10], b2c, NB2);

    // CSR build
    hipMemsetAsync(deg, 0, (size_t)N * 4, stream);
    hipMemsetAsync(csr, 0, (size_t)ET * 4, stream);
    int gE = (ET + 255) / 256;
    deg_kernel<<<gE, 256, 0, stream>>>(ei, E, N, deg);
    scan_kernel<<<1, 1024, 0, stream>>>(deg, rowptr, cursor, N);
    scatter_kernel<<<gE, 256, 0, stream>>>(ei, E, N, cursor, csr);

    int gWaveM = ((N + 15) / 16 + 3) / 4;
    int gNode  = (N + 3) / 4;

    // layer 1
    gemm_nt_kernel<512, 16><<<gWaveM, 256, 0, stream>>>(xc, w1c, h1, N);
    escore_kernel<4><<<gNode, 256, 0, stream>>>(h1, a1sc, a1dc, es, ed, N);
    aggregate_kernel<4, true, false><<<gNode, 256, 0, stream>>>(h1, es, ed, rowptr, csr, b1c,
                                                                out1, N, ET, flag);
    // layer 2 (h2 reuses h1 buffer)
    unsigned short* h2 = h1;
    gemm_nt_kernel<256, 8><<<gWaveM, 256, 0, stream>>>(out1, w2c, h2, N);
    escore_kernel<2><<<gNode, 256, 0, stream>>>(h2, a2sc, a2dc, es, ed, N);
    aggregate_kernel<2, false, true><<<gNode, 256, 0, stream>>>(h2, es, ed, rowptr, csr, b2c,
                                                                d_out, N, ET, flag);
}

// Round 6
// 519.016 us; speedup vs baseline: 1.3906x; 1.3906x over previous
//
#include <hip/hip_runtime.h>

// GAT 2-layer on gfx950. Inputs are f32 (auto-detected, converted to bf16).
// Round 6: (a) tiled 128x128 MFMA GEMM with LDS staging (was per-wave
// global-load GEMM, 128.7us latency-bound @ MfmaUtil 3.9%); (b) parallel
// 3-kernel scan (was serial single-block). Scratch allocated at dlopen.

typedef __bf16 bf16x8 __attribute__((ext_vector_type(8)));
typedef float f32x4 __attribute__((ext_vector_type(4)));

static void* g_scratch = nullptr;
#define SCRATCH_BYTES ((size_t)160 * 1024 * 1024)

__attribute__((constructor)) static void alloc_scratch_at_load() {
    if (hipMalloc(&g_scratch, SCRATCH_BYTES) != hipSuccess) g_scratch = nullptr;
}

__device__ __forceinline__ float bf2f(unsigned short u) {
    union { unsigned int i; float f; } v;
    v.i = ((unsigned int)u) << 16;
    return v.f;
}
__device__ __forceinline__ unsigned short f2bf(float f) {
    union { float f; unsigned int i; } v;
    v.f = f;
    unsigned int x = v.i;
    return (unsigned short)((x + 0x7fffu + ((x >> 16) & 1u)) >> 16); // RNE
}
__device__ __forceinline__ float fin(float v) {
    return (v == v && fabsf(v) <= 3.0e38f) ? v : 0.f;
}

// ---------------- dtype probe + convert ----------------

__global__ void probe_kernel(const unsigned int* __restrict__ xw, int* __restrict__ flag) {
    int lane = threadIdx.x; // 64 threads
    int cnt = 0;
    for (int i = lane; i < 1024; i += 64) {
        float v = bf2f((unsigned short)(xw[i] & 0xffffu));
        float a = fabsf(v);
        if (a >= 0.0078125f && a < 2.0f) cnt++;
    }
    #pragma unroll
    for (int off = 32; off; off >>= 1) cnt += __shfl_xor(cnt, off);
    if (lane == 0) *flag = (cnt < 512) ? 1 : 0; // 1 => f32 inputs
}

__global__ __launch_bounds__(256) void cvt_kernel(const void* __restrict__ src,
                                                  unsigned short* __restrict__ dst, int n,
                                                  const int* __restrict__ flag) {
    int i = blockIdx.x * 256 + threadIdx.x;
    if (i >= n) return;
    if (*flag) dst[i] = f2bf(((const float*)src)[i]);
    else       dst[i] = ((const unsigned short*)src)[i];
}

__global__ __launch_bounds__(256) void fill_kernel(unsigned short* __restrict__ out, int n,
                                                   float val) {
    int i = blockIdx.x * 256 + threadIdx.x;
    if (i < n) out[i] = f2bf(val);
}

// ---------------- CSR build ----------------

__global__ __launch_bounds__(256) void deg_kernel(const int* __restrict__ ei, int E, int N,
                                                  int* __restrict__ deg) {
    int i = blockIdx.x * 256 + threadIdx.x;
    int total = E + N;
    if (i < total) {
        int dst = (i < E) ? ei[E + i] : (i - E);
        if ((unsigned)dst < (unsigned)N) atomicAdd(&deg[dst], 1);
    }
}

// parallel scan: per-block sums -> 1-block scan of sums -> per-block write
__global__ __launch_bounds__(256) void scan_bsum_kernel(const int* __restrict__ deg,
                                                        int* __restrict__ bsum, int n) {
    int tid = threadIdx.x;
    int i = blockIdx.x * 256 + tid;
    int v = (i < n) ? deg[i] : 0;
    #pragma unroll
    for (int off = 32; off; off >>= 1) v += __shfl_xor(v, off);
    __shared__ int sh[4];
    if ((tid & 63) == 0) sh[tid >> 6] = v;
    __syncthreads();
    if (tid == 0) bsum[blockIdx.x] = sh[0] + sh[1] + sh[2] + sh[3];
}

__global__ __launch_bounds__(256) void scan_scan_kernel(int* __restrict__ bsum, int nb,
                                                        int* __restrict__ total) {
    // nb <= 256 (N <= 65536). Hillis-Steele inclusive, then make exclusive.
    __shared__ int sh[256];
    int tid = threadIdx.x;
    int v = (tid < nb) ? bsum[tid] : 0;
    sh[tid] = v;
    __syncthreads();
    #pragma unroll
    for (int off = 1; off < 256; off <<= 1) {
        int t = (tid >= off) ? sh[tid - off] : 0;
        __syncthreads();
        sh[tid] += t;
        __syncthreads();
    }
    if (tid < nb) bsum[tid] = sh[tid] - v; // exclusive block offset
    if (tid == 255) *total = sh[255];
}

__global__ __launch_bounds__(256) void scan_write_kernel(const int* __restrict__ deg,
                                                         const int* __restrict__ bsum,
                                                         int* __restrict__ rowptr,
                                                         int* __restrict__ cursor, int n) {
    __shared__ int sh[256];
    int tid = threadIdx.x;
    int i = blockIdx.x * 256 + tid;
    int v = (i < n) ? deg[i] : 0;
    sh[tid] = v;
    __syncthreads();
    #pragma unroll
    for (int off = 1; off < 256; off <<= 1) {
        int t = (tid >= off) ? sh[tid - off] : 0;
        __syncthreads();
        sh[tid] += t;
        __syncthreads();
    }
    if (i < n) {
        int excl = sh[tid] - v + bsum[blockIdx.x];
        rowptr[i] = excl;
        cursor[i] = excl;
    }
}

__global__ __launch_bounds__(256) void scatter_kernel(const int* __restrict__ ei, int E, int N,
                                                      int* __restrict__ cursor,
                                                      int* __restrict__ csr) {
    int i = blockIdx.x * 256 + threadIdx.x;
    int total = E + N;
    if (i < total) {
        int s, d;
        if (i < E) { s = ei[i]; d = ei[E + i]; }
        else       { s = i - E; d = i - E; }
        if ((unsigned)d >= (unsigned)N) return;
        int pos = atomicAdd(&cursor[d], 1);
        if ((unsigned)pos < (unsigned)total) csr[pos] = s;
    }
}

// ---------------- tiled GEMM: C[M,Nc] = A[M,K] * B[Nc,K]^T ----------------
// 128x128 tile per 256-thread workgroup; BK=64 LDS staging, XOR column swizzle.
// 4 waves in 2x2 grid, each computing 64x64 via 4x4 MFMA 16x16x32 bf16 tiles.
// LDS: logical (row, col=cg*8+j) stored at phys row*64 + ((cg^(row&7))*8) + j.

template <int K, int NTN> // NTN = number of 128-col tiles = Nc/128
__global__ __launch_bounds__(256) void gemm_tile_kernel(const unsigned short* __restrict__ A,
                                                        const unsigned short* __restrict__ B,
                                                        unsigned short* __restrict__ C, int M) {
    __shared__ __align__(16) unsigned short As[128 * 64];
    __shared__ __align__(16) unsigned short Bs[128 * 64];
    const int Nc = NTN * 128;
    int bx = blockIdx.x;
    int mt = bx / NTN, nt = bx % NTN;
    int row0 = mt * 128, n0 = nt * 128;
    int t = threadIdx.x;
    int lane = t & 63, w = t >> 6;
    int wr = w >> 1, wc = w & 1;
    int r = lane & 15, kq = lane >> 4;

    f32x4 acc[4][4];
    #pragma unroll
    for (int i = 0; i < 4; ++i)
        #pragma unroll
        for (int j = 0; j < 4; ++j) acc[i][j] = (f32x4){0.f, 0.f, 0.f, 0.f};

    for (int k0 = 0; k0 < K; k0 += 64) {
        #pragma unroll
        for (int rr = 0; rr < 4; ++rr) {
            int idx = rr * 256 + t;          // 0..1023 over 128 rows x 8 col-groups
            int row = idx >> 3, cg = idx & 7;
            int arow = row0 + row; if (arow >= M) arow = M - 1;
            bf16x8 va = *reinterpret_cast<const bf16x8*>(A + (size_t)arow * K + k0 + cg * 8);
            bf16x8 vb = *reinterpret_cast<const bf16x8*>(B + (size_t)(n0 + row) * K + k0 + cg * 8);
            int pc = ((cg ^ (row & 7)) * 8);
            *reinterpret_cast<bf16x8*>(As + row * 64 + pc) = va;
            *reinterpret_cast<bf16x8*>(Bs + row * 64 + pc) = vb;
        }
        __syncthreads();
        #pragma unroll
        for (int ks = 0; ks < 64; ks += 32) {
            int cg = (ks >> 3) + kq; // logical col-group for this lane's k slice
            bf16x8 af[4], bf[4];
            #pragma unroll
            for (int i = 0; i < 4; ++i) {
                int rowA = wr * 64 + i * 16 + r;
                af[i] = *reinterpret_cast<const bf16x8*>(As + rowA * 64 + ((cg ^ (rowA & 7)) * 8));
                int rowB = wc * 64 + i * 16 + r;
                bf[i] = *reinterpret_cast<const bf16x8*>(Bs + rowB * 64 + ((cg ^ (rowB & 7)) * 8));
            }
            #pragma unroll
            for (int i = 0; i < 4; ++i)
                #pragma unroll
                for (int j = 0; j < 4; ++j)
                    acc[i][j] = __builtin_amdgcn_mfma_f32_16x16x32_bf16(af[i], bf[j], acc[i][j], 0, 0, 0);
        }
        __syncthreads();
    }

    // C/D layout: col = lane&15 (r), row = (lane>>4)*4 + q (kq)
    #pragma unroll
    for (int i = 0; i < 4; ++i) {
        #pragma unroll
        for (int q = 0; q < 4; ++q) {
            int row = row0 + wr * 64 + i * 16 + kq * 4 + q;
            if (row < M) {
                #pragma unroll
                for (int j = 0; j < 4; ++j) {
                    int col = n0 + wc * 64 + j * 16 + r;
                    C[(size_t)row * Nc + col] = f2bf(fin(acc[i][j][q]));
                }
            }
        }
    }
}

// ---------------- per-node attention scores ----------------

template <int CPL> // channels per lane; DOUT = 64*CPL
__global__ __launch_bounds__(256) void escore_kernel(const unsigned short* __restrict__ h,
                                                     const unsigned short* __restrict__ a_src,
                                                     const unsigned short* __restrict__ a_dst,
                                                     float* __restrict__ es,
                                                     float* __restrict__ ed, int n) {
    int w = blockIdx.x * 4 + (threadIdx.x >> 6);
    if (w >= n) return;
    int lane = threadIdx.x & 63;
    const int DOUT = CPL * 64;
    float s1 = 0.f, s2 = 0.f;
    #pragma unroll
    for (int i = 0; i < CPL; ++i) {
        float hv = bf2f(h[(size_t)w * DOUT + lane * CPL + i]);
        s1 += hv * bf2f(a_src[lane * CPL + i]);
        s2 += hv * bf2f(a_dst[lane * CPL + i]);
    }
    #pragma unroll
    for (int off = 32; off; off >>= 1) {
        s1 += __shfl_xor(s1, off);
        s2 += __shfl_xor(s2, off);
    }
    if (lane == 0) { es[w] = fin(s1); ed[w] = fin(s2); }
}

// ---------------- per-dst softmax + gather aggregation ----------------

template <int CPL, bool RELU, bool DUAL>
__global__ __launch_bounds__(256) void aggregate_kernel(const unsigned short* __restrict__ h,
                                                        const float* __restrict__ es,
                                                        const float* __restrict__ ed,
                                                        const int* __restrict__ rowptr,
                                                        const int* __restrict__ csr,
                                                        const unsigned short* __restrict__ bias,
                                                        void* __restrict__ out,
                                                        int n, int ET,
                                                        const int* __restrict__ flagp) {
    int w = blockIdx.x * 4 + (threadIdx.x >> 6);
    if (w >= n) return;
    int lane = threadIdx.x & 63;
    const int DOUT = CPL * 64;
    int f32out = DUAL ? flagp[0] : 0;
    int start = rowptr[w], end = rowptr[w + 1];
    start = max(0, min(start, ET));
    end = max(start, min(end, ET));
    float edv = ed[w];

    float m = -1e30f;
    for (int j = start + lane; j < end; j += 64) {
        int s = csr[j];
        s = ((unsigned)s < (unsigned)n) ? s : 0;
        float v = es[s] + edv;
        v = (v > 0.f) ? v : 0.2f * v;
        m = fmaxf(m, v);
    }
    #pragma unroll
    for (int off = 32; off; off >>= 1) m = fmaxf(m, __shfl_xor(m, off));
    if (!(m > -1e29f)) m = 0.f;

    float ssum = 0.f;
    float acc[CPL];
    #pragma unroll
    for (int i = 0; i < CPL; ++i) acc[i] = 0.f;

    for (int base = start; base < end; base += 64) {
        int j = base + lane;
        float p = 0.f;
        int sidx = 0;
        if (j < end) {
            int s = csr[j];
            sidx = ((unsigned)s < (unsigned)n) ? s : 0;
            float v = es[sidx] + edv;
            v = (v > 0.f) ? v : 0.2f * v;
            p = __expf(v - m);
        }
        ssum += p;
        int cnt = min(64, end - base);
        for (int jj = 0; jj < cnt; ++jj) {
            float pj = __shfl(p, jj);
            int sj = __shfl(sidx, jj);
            const unsigned short* hp = h + (size_t)sj * DOUT + lane * CPL;
            if (CPL == 4) {
                uint2 u = *reinterpret_cast<const uint2*>(hp);
                acc[0] += pj * bf2f((unsigned short)(u.x & 0xffff));
                acc[1] += pj * bf2f((unsigned short)(u.x >> 16));
                acc[2] += pj * bf2f((unsigned short)(u.y & 0xffff));
                acc[3] += pj * bf2f((unsigned short)(u.y >> 16));
            } else {
                unsigned int u = *reinterpret_cast<const unsigned int*>(hp);
                acc[0] += pj * bf2f((unsigned short)(u & 0xffff));
                acc[1] += pj * bf2f((unsigned short)(u >> 16));
            }
        }
    }
    #pragma unroll
    for (int off = 32; off; off >>= 1) ssum += __shfl_xor(ssum, off);
    float inv = 1.f / fmaxf(ssum, 1e-20f);
    #pragma unroll
    for (int i = 0; i < CPL; ++i) {
        float o = acc[i] * inv + bf2f(bias[lane * CPL + i]);
        if (RELU) o = fmaxf(o, 0.f);
        o = fin(o);
        size_t idx = (size_t)w * DOUT + lane * CPL + i;
        if (DUAL && f32out) ((float*)out)[idx] = o;
        else                ((unsigned short*)out)[idx] = f2bf(o);
    }
}

// ---------------- launch ----------------

extern "C" void kernel_launch(void* const* d_in, const int* in_sizes, int n_in,
                              void* d_out, int out_size, void* d_ws, size_t ws_size,
                              hipStream_t stream) {
    int gOut = (out_size + 255) / 256;
    if (n_in != 11) {
        fill_kernel<<<gOut, 256, 0, stream>>>((unsigned short*)d_out, out_size, 999.f);
        return;
    }

    const int N = in_sizes[0] / 512; // 50000
    const int E = in_sizes[1] / 2;   // 800000
    const int ET = E + N;

    const int NX  = in_sizes[0];
    const int NW1 = in_sizes[3];
    const int NA  = in_sizes[4];
    const int NB1 = in_sizes[6];
    const int NW2 = in_sizes[7];
    const int NA2 = in_sizes[8];
    const int NB2 = in_sizes[10];

    size_t off = 0;
    auto reserve = [&](size_t bytes) {
        size_t o = off;
        off = (off + bytes + 255) & ~(size_t)255;
        return o;
    };
    size_t o_flag   = reserve(256);
    size_t o_total  = reserve(256);
    size_t o_es     = reserve((size_t)N * 4);
    size_t o_ed     = reserve((size_t)N * 4);
    size_t o_deg    = reserve((size_t)N * 4);
    size_t o_rowptr = reserve((size_t)(N + 1) * 4);
    size_t o_cursor = reserve((size_t)N * 4);
    size_t o_bsum   = reserve(((size_t)N / 256 + 2) * 4);
    size_t o_csr    = reserve((size_t)ET * 4);
    size_t o_h1     = reserve((size_t)N * 256 * 2);
    size_t o_out1   = reserve((size_t)N * 256 * 2);
    size_t o_xc     = reserve((size_t)NX * 2);
    size_t o_w1c    = reserve((size_t)NW1 * 2);
    size_t o_a1s    = reserve((size_t)NA * 2);
    size_t o_a1d    = reserve((size_t)NA * 2);
    size_t o_b1c    = reserve((size_t)NB1 * 2);
    size_t o_w2c    = reserve((size_t)NW2 * 2);
    size_t o_a2s    = reserve((size_t)NA2 * 2);
    size_t o_a2d    = reserve((size_t)NA2 * 2);
    size_t o_b2c    = reserve((size_t)NB2 * 2);
    size_t need = off;

    char* base = nullptr;
    if (ws_size >= need) base = (char*)d_ws;
    else if (g_scratch && SCRATCH_BYTES >= need) base = (char*)g_scratch;
    if (!base) {
        fill_kernel<<<gOut, 256, 0, stream>>>((unsigned short*)d_out, out_size,
                                              100.f + (float)(ws_size >> 20));
        return;
    }

    int*   flag    = (int*)(base + o_flag);
    float* es      = (float*)(base + o_es);
    float* ed      = (float*)(base + o_ed);
    int*   deg     = (int*)(base + o_deg);
    int*   rowptr  = (int*)(base + o_rowptr);
    int*   cursor  = (int*)(base + o_cursor);
    int*   bsum    = (int*)(base + o_bsum);
    int*   csr     = (int*)(base + o_csr);
    unsigned short* h1   = (unsigned short*)(base + o_h1);
    unsigned short* out1 = (unsigned short*)(base + o_out1);
    unsigned short* xc   = (unsigned short*)(base + o_xc);
    unsigned short* w1c  = (unsigned short*)(base + o_w1c);
    unsigned short* a1sc = (unsigned short*)(base + o_a1s);
    unsigned short* a1dc = (unsigned short*)(base + o_a1d);
    unsigned short* b1c  = (unsigned short*)(base + o_b1c);
    unsigned short* w2c  = (unsigned short*)(base + o_w2c);
    unsigned short* a2sc = (unsigned short*)(base + o_a2s);
    unsigned short* a2dc = (unsigned short*)(base + o_a2d);
    unsigned short* b2c  = (unsigned short*)(base + o_b2c);
    (void)o_total;

    const int* ei = (const int*)d_in[1];

    probe_kernel<<<1, 64, 0, stream>>>((const unsigned int*)d_in[0], flag);
    auto cvt = [&](const void* src, unsigned short* dst, int n) {
        cvt_kernel<<<(n + 255) / 256, 256, 0, stream>>>(src, dst, n, flag);
    };
    cvt(d_in[0], xc, NX);
    cvt(d_in[3], w1c, NW1);
    cvt(d_in[4], a1sc, NA);
    cvt(d_in[5], a1dc, NA);
    cvt(d_in[6], b1c, NB1);
    cvt(d_in[7], w2c, NW2);
    cvt(d_in[8], a2sc, NA2);
    cvt(d_in[9], a2dc, NA2);
    cvt(d_in[10], b2c, NB2);

    // CSR build
    hipMemsetAsync(deg, 0, (size_t)N * 4, stream);
    hipMemsetAsync(csr, 0, (size_t)ET * 4, stream);
    int gE = (ET + 255) / 256;
    int gN256 = (N + 255) / 256; // 196 blocks (<=256 assumed: N<=65536)
    deg_kernel<<<gE, 256, 0, stream>>>(ei, E, N, deg);
    scan_bsum_kernel<<<gN256, 256, 0, stream>>>(deg, bsum, N);
    scan_scan_kernel<<<1, 256, 0, stream>>>(bsum, gN256, rowptr + N);
    scan_write_kernel<<<gN256, 256, 0, stream>>>(deg, bsum, rowptr, cursor, N);
    scatter_kernel<<<gE, 256, 0, stream>>>(ei, E, N, cursor, csr);

    int numM = (N + 127) / 128; // 391
    int gNode = (N + 3) / 4;

    // layer 1
    gemm_tile_kernel<512, 2><<<numM * 2, 256, 0, stream>>>(xc, w1c, h1, N);
    escore_kernel<4><<<gNode, 256, 0, stream>>>(h1, a1sc, a1dc, es, ed, N);
    aggregate_kernel<4, true, false><<<gNode, 256, 0, stream>>>(h1, es, ed, rowptr, csr, b1c,
                                                                out1, N, ET, flag);
    // layer 2 (h2 reuses h1 buffer)
    unsigned short* h2 = h1;
    gemm_tile_kernel<256, 1><<<numM, 256, 0, stream>>>(out1, w2c, h2, N);
    escore_kernel<2><<<gNode, 256, 0, stream>>>(h2, a2sc, a2dc, es, ed, N);
    aggregate_kernel<2, false, true><<<gNode, 256, 0, stream>>>(h2, es, ed, rowptr, csr, b2c,
                                                                d_out, N, ET, flag);
}

// Round 7
// 445.910 us; speedup vs baseline: 1.6185x; 1.1639x over previous
//
#include <hip/hip_runtime.h>

// GAT 2-layer on gfx950. Inputs f32 (auto-detected, converted to bf16).
// Round 7: multi-edge dwordx4 gather in aggregate (2 edges/wave L1, 4 L2),
// vectorized escore, batched small converts, float4 x-convert.

typedef __bf16 bf16x8 __attribute__((ext_vector_type(8)));
typedef float f32x4 __attribute__((ext_vector_type(4)));

static void* g_scratch = nullptr;
#define SCRATCH_BYTES ((size_t)160 * 1024 * 1024)

__attribute__((constructor)) static void alloc_scratch_at_load() {
    if (hipMalloc(&g_scratch, SCRATCH_BYTES) != hipSuccess) g_scratch = nullptr;
}

__device__ __forceinline__ float bf2f(unsigned short u) {
    union { unsigned int i; float f; } v;
    v.i = ((unsigned int)u) << 16;
    return v.f;
}
__device__ __forceinline__ unsigned short f2bf(float f) {
    union { float f; unsigned int i; } v;
    v.f = f;
    unsigned int x = v.i;
    return (unsigned short)((x + 0x7fffu + ((x >> 16) & 1u)) >> 16); // RNE
}
__device__ __forceinline__ float fin(float v) {
    return (v == v && fabsf(v) <= 3.0e38f) ? v : 0.f;
}

// ---------------- dtype probe + converts ----------------

__global__ void probe_kernel(const unsigned int* __restrict__ xw, int* __restrict__ flag) {
    int lane = threadIdx.x; // 64 threads
    int cnt = 0;
    for (int i = lane; i < 1024; i += 64) {
        float v = bf2f((unsigned short)(xw[i] & 0xffffu));
        float a = fabsf(v);
        if (a >= 0.0078125f && a < 2.0f) cnt++;
    }
    #pragma unroll
    for (int off = 32; off; off >>= 1) cnt += __shfl_xor(cnt, off);
    if (lane == 0) *flag = (cnt < 512) ? 1 : 0; // 1 => f32 inputs
}

// big x convert: 4 elements per thread
__global__ __launch_bounds__(256) void cvtx_kernel(const void* __restrict__ src,
                                                   unsigned short* __restrict__ dst, int n4,
                                                   const int* __restrict__ flag) {
    int i = blockIdx.x * 256 + threadIdx.x;
    if (i >= n4) return;
    if (*flag) {
        float4 f = ((const float4*)src)[i];
        ushort4 o;
        o.x = f2bf(f.x); o.y = f2bf(f.y); o.z = f2bf(f.z); o.w = f2bf(f.w);
        ((ushort4*)dst)[i] = o;
    } else {
        ((uint2*)dst)[i] = ((const uint2*)src)[i];
    }
}

struct CvtBatch {
    const void* src[8];
    unsigned short* dst[8];
    int n[8];
};

__global__ __launch_bounds__(256) void cvt_batch_kernel(CvtBatch b, const int* __restrict__ flag) {
    int i = blockIdx.x * 256 + threadIdx.x;
    int f = *flag;
    #pragma unroll
    for (int s = 0; s < 8; ++s) {
        if (i < b.n[s]) {
            if (f) b.dst[s][i] = f2bf(((const float*)b.src[s])[i]);
            else   b.dst[s][i] = ((const unsigned short*)b.src[s])[i];
            return;
        }
        i -= b.n[s];
    }
}

__global__ __launch_bounds__(256) void fill_kernel(unsigned short* __restrict__ out, int n,
                                                   float val) {
    int i = blockIdx.x * 256 + threadIdx.x;
    if (i < n) out[i] = f2bf(val);
}

// ---------------- CSR build ----------------

__global__ __launch_bounds__(256) void deg_kernel(const int* __restrict__ ei, int E, int N,
                                                  int* __restrict__ deg) {
    int i = blockIdx.x * 256 + threadIdx.x;
    int total = E + N;
    if (i < total) {
        int dst = (i < E) ? ei[E + i] : (i - E);
        if ((unsigned)dst < (unsigned)N) atomicAdd(&deg[dst], 1);
    }
}

__global__ __launch_bounds__(256) void scan_bsum_kernel(const int* __restrict__ deg,
                                                        int* __restrict__ bsum, int n) {
    int tid = threadIdx.x;
    int i = blockIdx.x * 256 + tid;
    int v = (i < n) ? deg[i] : 0;
    #pragma unroll
    for (int off = 32; off; off >>= 1) v += __shfl_xor(v, off);
    __shared__ int sh[4];
    if ((tid & 63) == 0) sh[tid >> 6] = v;
    __syncthreads();
    if (tid == 0) bsum[blockIdx.x] = sh[0] + sh[1] + sh[2] + sh[3];
}

__global__ __launch_bounds__(256) void scan_scan_kernel(int* __restrict__ bsum, int nb,
                                                        int* __restrict__ total) {
    __shared__ int sh[256];
    int tid = threadIdx.x;
    int v = (tid < nb) ? bsum[tid] : 0;
    sh[tid] = v;
    __syncthreads();
    #pragma unroll
    for (int off = 1; off < 256; off <<= 1) {
        int t = (tid >= off) ? sh[tid - off] : 0;
        __syncthreads();
        sh[tid] += t;
        __syncthreads();
    }
    if (tid < nb) bsum[tid] = sh[tid] - v;
    if (tid == 255) *total = sh[255];
}

__global__ __launch_bounds__(256) void scan_write_kernel(const int* __restrict__ deg,
                                                         const int* __restrict__ bsum,
                                                         int* __restrict__ rowptr,
                                                         int* __restrict__ cursor, int n) {
    __shared__ int sh[256];
    int tid = threadIdx.x;
    int i = blockIdx.x * 256 + tid;
    int v = (i < n) ? deg[i] : 0;
    sh[tid] = v;
    __syncthreads();
    #pragma unroll
    for (int off = 1; off < 256; off <<= 1) {
        int t = (tid >= off) ? sh[tid - off] : 0;
        __syncthreads();
        sh[tid] += t;
        __syncthreads();
    }
    if (i < n) {
        int excl = sh[tid] - v + bsum[blockIdx.x];
        rowptr[i] = excl;
        cursor[i] = excl;
    }
}

__global__ __launch_bounds__(256) void scatter_kernel(const int* __restrict__ ei, int E, int N,
                                                      int* __restrict__ cursor,
                                                      int* __restrict__ csr) {
    int i = blockIdx.x * 256 + threadIdx.x;
    int total = E + N;
    if (i < total) {
        int s, d;
        if (i < E) { s = ei[i]; d = ei[E + i]; }
        else       { s = i - E; d = i - E; }
        if ((unsigned)d >= (unsigned)N) return;
        int pos = atomicAdd(&cursor[d], 1);
        if ((unsigned)pos < (unsigned)total) csr[pos] = s;
    }
}

// ---------------- tiled GEMM: C[M,Nc] = A[M,K] * B[Nc,K]^T ----------------

template <int K, int NTN>
__global__ __launch_bounds__(256) void gemm_tile_kernel(const unsigned short* __restrict__ A,
                                                        const unsigned short* __restrict__ B,
                                                        unsigned short* __restrict__ C, int M) {
    __shared__ __align__(16) unsigned short As[128 * 64];
    __shared__ __align__(16) unsigned short Bs[128 * 64];
    const int Nc = NTN * 128;
    int bx = blockIdx.x;
    int mt = bx / NTN, nt = bx % NTN;
    int row0 = mt * 128, n0 = nt * 128;
    int t = threadIdx.x;
    int lane = t & 63, w = t >> 6;
    int wr = w >> 1, wc = w & 1;
    int r = lane & 15, kq = lane >> 4;

    f32x4 acc[4][4];
    #pragma unroll
    for (int i = 0; i < 4; ++i)
        #pragma unroll
        for (int j = 0; j < 4; ++j) acc[i][j] = (f32x4){0.f, 0.f, 0.f, 0.f};

    for (int k0 = 0; k0 < K; k0 += 64) {
        #pragma unroll
        for (int rr = 0; rr < 4; ++rr) {
            int idx = rr * 256 + t;
            int row = idx >> 3, cg = idx & 7;
            int arow = row0 + row; if (arow >= M) arow = M - 1;
            bf16x8 va = *reinterpret_cast<const bf16x8*>(A + (size_t)arow * K + k0 + cg * 8);
            bf16x8 vb = *reinterpret_cast<const bf16x8*>(B + (size_t)(n0 + row) * K + k0 + cg * 8);
            int pc = ((cg ^ (row & 7)) * 8);
            *reinterpret_cast<bf16x8*>(As + row * 64 + pc) = va;
            *reinterpret_cast<bf16x8*>(Bs + row * 64 + pc) = vb;
        }
        __syncthreads();
        #pragma unroll
        for (int ks = 0; ks < 64; ks += 32) {
            int cg = (ks >> 3) + kq;
            bf16x8 af[4], bfr[4];
            #pragma unroll
            for (int i = 0; i < 4; ++i) {
                int rowA = wr * 64 + i * 16 + r;
                af[i] = *reinterpret_cast<const bf16x8*>(As + rowA * 64 + ((cg ^ (rowA & 7)) * 8));
                int rowB = wc * 64 + i * 16 + r;
                bfr[i] = *reinterpret_cast<const bf16x8*>(Bs + rowB * 64 + ((cg ^ (rowB & 7)) * 8));
            }
            #pragma unroll
            for (int i = 0; i < 4; ++i)
                #pragma unroll
                for (int j = 0; j < 4; ++j)
                    acc[i][j] = __builtin_amdgcn_mfma_f32_16x16x32_bf16(af[i], bfr[j], acc[i][j], 0, 0, 0);
        }
        __syncthreads();
    }

    #pragma unroll
    for (int i = 0; i < 4; ++i) {
        #pragma unroll
        for (int q = 0; q < 4; ++q) {
            int row = row0 + wr * 64 + i * 16 + kq * 4 + q;
            if (row < M) {
                #pragma unroll
                for (int j = 0; j < 4; ++j) {
                    int col = n0 + wc * 64 + j * 16 + r;
                    C[(size_t)row * Nc + col] = f2bf(fin(acc[i][j][q]));
                }
            }
        }
    }
}

// ---------------- per-node attention scores ----------------

template <int CPL> // 4 (256ch) or 2 (128ch)
__global__ __launch_bounds__(256) void escore_kernel(const unsigned short* __restrict__ h,
                                                     const unsigned short* __restrict__ a_src,
                                                     const unsigned short* __restrict__ a_dst,
                                                     float* __restrict__ es,
                                                     float* __restrict__ ed, int n) {
    int w = blockIdx.x * 4 + (threadIdx.x >> 6);
    if (w >= n) return;
    int lane = threadIdx.x & 63;
    const int DOUT = CPL * 64;
    float s1 = 0.f, s2 = 0.f;
    if (CPL == 4) {
        uint2 uh = *(const uint2*)(h + (size_t)w * DOUT + lane * 4);
        uint2 us = *(const uint2*)(a_src + lane * 4);
        uint2 ud = *(const uint2*)(a_dst + lane * 4);
        float h0 = bf2f(uh.x & 0xffff), h1v = bf2f(uh.x >> 16);
        float h2v = bf2f(uh.y & 0xffff), h3 = bf2f(uh.y >> 16);
        s1 = h0 * bf2f(us.x & 0xffff) + h1v * bf2f(us.x >> 16)
           + h2v * bf2f(us.y & 0xffff) + h3 * bf2f(us.y >> 16);
        s2 = h0 * bf2f(ud.x & 0xffff) + h1v * bf2f(ud.x >> 16)
           + h2v * bf2f(ud.y & 0xffff) + h3 * bf2f(ud.y >> 16);
    } else {
        unsigned int uh = *(const unsigned int*)(h + (size_t)w * DOUT + lane * 2);
        unsigned int us = *(const unsigned int*)(a_src + lane * 2);
        unsigned int ud = *(const unsigned int*)(a_dst + lane * 2);
        float h0 = bf2f(uh & 0xffff), h1v = bf2f(uh >> 16);
        s1 = h0 * bf2f(us & 0xffff) + h1v * bf2f(us >> 16);
        s2 = h0 * bf2f(ud & 0xffff) + h1v * bf2f(ud >> 16);
    }
    #pragma unroll
    for (int off = 32; off; off >>= 1) {
        s1 += __shfl_xor(s1, off);
        s2 += __shfl_xor(s2, off);
    }
    if (lane == 0) { es[w] = fin(s1); ed[w] = fin(s2); }
}

// ---------------- per-dst softmax + multi-edge gather aggregation ----------------
// CH channels; lanes split into EPW=64/(CH/8) edge slots, each slot LPE=CH/8 lanes
// reading 8 channels (dwordx4) per edge.

template <int CH, bool RELU, bool DUAL>
__global__ __launch_bounds__(256) void aggregate_kernel(const unsigned short* __restrict__ h,
                                                        const float* __restrict__ es,
                                                        const float* __restrict__ ed,
                                                        const int* __restrict__ rowptr,
                                                        const int* __restrict__ csr,
                                                        const unsigned short* __restrict__ bias,
                                                        void* __restrict__ out,
                                                        int n, int ET,
                                                        const int* __restrict__ flagp) {
    constexpr int LPE = CH / 8;   // lanes per edge (8 ch each)
    int w = blockIdx.x * 4 + (threadIdx.x >> 6); // one wave per dst node
    if (w >= n) return;
    int lane = threadIdx.x & 63;
    int eh = lane / LPE;          // edge slot
    int cl = lane % LPE;          // channel group: ch = cl*8..cl*8+7
    int f32out = DUAL ? flagp[0] : 0;
    int start = rowptr[w], end = rowptr[w + 1];
    start = max(0, min(start, ET));
    end = max(start, min(end, ET));
    float edv = ed[w];

    // pass 0: segment max of leaky(e_src+e_dst)
    float m = -1e30f;
    for (int j = start + lane; j < end; j += 64) {
        int s = csr[j];
        s = ((unsigned)s < (unsigned)n) ? s : 0;
        float v = es[s] + edv;
        v = (v > 0.f) ? v : 0.2f * v;
        m = fmaxf(m, v);
    }
    #pragma unroll
    for (int off = 32; off; off >>= 1) m = fmaxf(m, __shfl_xor(m, off));
    if (!(m > -1e29f)) m = 0.f;

    float ssum = 0.f;
    float acc[8];
    #pragma unroll
    for (int i = 0; i < 8; ++i) acc[i] = 0.f;

    for (int base = start; base < end; base += 64) {
        int j = base + lane;
        float p = 0.f;
        int sidx = 0;
        if (j < end) {
            int s = csr[j];
            sidx = ((unsigned)s < (unsigned)n) ? s : 0;
            float v = es[sidx] + edv;
            v = (v > 0.f) ? v : 0.2f * v;
            p = __expf(v - m);
        }
        ssum += p;
        int cnt = min(64, end - base);
        constexpr int EPW = 64 / LPE;
        for (int g = 0; g < cnt; g += EPW) {
            int sl = g + eh; if (sl > 63) sl = 63;
            float pj = __shfl(p, sl);
            int sj = __shfl(sidx, sl);
            if (pj > 0.f) { // inactive/tail lanes (p==0) skip load & fma
                uint4 u = *(const uint4*)(h + (size_t)sj * CH + cl * 8);
                acc[0] += pj * bf2f((unsigned short)(u.x & 0xffff));
                acc[1] += pj * bf2f((unsigned short)(u.x >> 16));
                acc[2] += pj * bf2f((unsigned short)(u.y & 0xffff));
                acc[3] += pj * bf2f((unsigned short)(u.y >> 16));
                acc[4] += pj * bf2f((unsigned short)(u.z & 0xffff));
                acc[5] += pj * bf2f((unsigned short)(u.z >> 16));
                acc[6] += pj * bf2f((unsigned short)(u.w & 0xffff));
                acc[7] += pj * bf2f((unsigned short)(u.w >> 16));
            }
        }
    }
    #pragma unroll
    for (int off = 32; off; off >>= 1) ssum += __shfl_xor(ssum, off);
    // reduce edge slots (lanes with same cl, distance multiples of LPE)
    #pragma unroll
    for (int off = 32; off >= LPE; off >>= 1)
        #pragma unroll
        for (int i = 0; i < 8; ++i) acc[i] += __shfl_xor(acc[i], off);

    if (lane < LPE) {
        float inv = 1.f / fmaxf(ssum, 1e-20f);
        uint4 ub = *(const uint4*)(bias + cl * 8);
        float bv[8] = {
            bf2f((unsigned short)(ub.x & 0xffff)), bf2f((unsigned short)(ub.x >> 16)),
            bf2f((unsigned short)(ub.y & 0xffff)), bf2f((unsigned short)(ub.y >> 16)),
            bf2f((unsigned short)(ub.z & 0xffff)), bf2f((unsigned short)(ub.z >> 16)),
            bf2f((unsigned short)(ub.w & 0xffff)), bf2f((unsigned short)(ub.w >> 16))};
        float o[8];
        #pragma unroll
        for (int i = 0; i < 8; ++i) {
            float v = acc[i] * inv + bv[i];
            if (RELU) v = fmaxf(v, 0.f);
            o[i] = fin(v);
        }
        size_t idx = (size_t)w * CH + cl * 8;
        if (DUAL && f32out) {
            float4* fp = (float4*)((float*)out + idx);
            fp[0] = (float4){o[0], o[1], o[2], o[3]};
            fp[1] = (float4){o[4], o[5], o[6], o[7]};
        } else {
            uint4 pu;
            pu.x = (unsigned)f2bf(o[0]) | ((unsigned)f2bf(o[1]) << 16);
            pu.y = (unsigned)f2bf(o[2]) | ((unsigned)f2bf(o[3]) << 16);
            pu.z = (unsigned)f2bf(o[4]) | ((unsigned)f2bf(o[5]) << 16);
            pu.w = (unsigned)f2bf(o[6]) | ((unsigned)f2bf(o[7]) << 16);
            *(uint4*)((unsigned short*)out + idx) = pu;
        }
    }
}

// ---------------- launch ----------------

extern "C" void kernel_launch(void* const* d_in, const int* in_sizes, int n_in,
                              void* d_out, int out_size, void* d_ws, size_t ws_size,
                              hipStream_t stream) {
    int gOut = (out_size + 255) / 256;
    if (n_in != 11) {
        fill_kernel<<<gOut, 256, 0, stream>>>((unsigned short*)d_out, out_size, 999.f);
        return;
    }

    const int N = in_sizes[0] / 512; // 50000
    const int E = in_sizes[1] / 2;   // 800000
    const int ET = E + N;

    const int NX  = in_sizes[0];
    const int NW1 = in_sizes[3];
    const int NA  = in_sizes[4];
    const int NB1 = in_sizes[6];
    const int NW2 = in_sizes[7];
    const int NA2 = in_sizes[8];
    const int NB2 = in_sizes[10];

    size_t off = 0;
    auto reserve = [&](size_t bytes) {
        size_t o = off;
        off = (off + bytes + 255) & ~(size_t)255;
        return o;
    };
    size_t o_flag   = reserve(256);
    size_t o_es     = reserve((size_t)N * 4);
    size_t o_ed     = reserve((size_t)N * 4);
    size_t o_deg    = reserve((size_t)N * 4);
    size_t o_rowptr = reserve((size_t)(N + 1) * 4);
    size_t o_cursor = reserve((size_t)N * 4);
    size_t o_bsum   = reserve(((size_t)N / 256 + 2) * 4);
    size_t o_csr    = reserve((size_t)ET * 4);
    size_t o_h1     = reserve((size_t)N * 256 * 2);
    size_t o_out1   = reserve((size_t)N * 256 * 2);
    size_t o_xc     = reserve((size_t)NX * 2);
    size_t o_w1c    = reserve((size_t)NW1 * 2);
    size_t o_a1s    = reserve((size_t)NA * 2);
    size_t o_a1d    = reserve((size_t)NA * 2);
    size_t o_b1c    = reserve((size_t)NB1 * 2);
    size_t o_w2c    = reserve((size_t)NW2 * 2);
    size_t o_a2s    = reserve((size_t)NA2 * 2);
    size_t o_a2d    = reserve((size_t)NA2 * 2);
    size_t o_b2c    = reserve((size_t)NB2 * 2);
    size_t need = off;

    char* base = nullptr;
    if (ws_size >= need) base = (char*)d_ws;
    else if (g_scratch && SCRATCH_BYTES >= need) base = (char*)g_scratch;
    if (!base) {
        fill_kernel<<<gOut, 256, 0, stream>>>((unsigned short*)d_out, out_size,
                                              100.f + (float)(ws_size >> 20));
        return;
    }

    int*   flag    = (int*)(base + o_flag);
    float* es      = (float*)(base + o_es);
    float* ed      = (float*)(base + o_ed);
    int*   deg     = (int*)(base + o_deg);
    int*   rowptr  = (int*)(base + o_rowptr);
    int*   cursor  = (int*)(base + o_cursor);
    int*   bsum    = (int*)(base + o_bsum);
    int*   csr     = (int*)(base + o_csr);
    unsigned short* h1   = (unsigned short*)(base + o_h1);
    unsigned short* out1 = (unsigned short*)(base + o_out1);
    unsigned short* xc   = (unsigned short*)(base + o_xc);
    unsigned short* w1c  = (unsigned short*)(base + o_w1c);
    unsigned short* a1sc = (unsigned short*)(base + o_a1s);
    unsigned short* a1dc = (unsigned short*)(base + o_a1d);
    unsigned short* b1c  = (unsigned short*)(base + o_b1c);
    unsigned short* w2c  = (unsigned short*)(base + o_w2c);
    unsigned short* a2sc = (unsigned short*)(base + o_a2s);
    unsigned short* a2dc = (unsigned short*)(base + o_a2d);
    unsigned short* b2c  = (unsigned short*)(base + o_b2c);

    const int* ei = (const int*)d_in[1];

    probe_kernel<<<1, 64, 0, stream>>>((const unsigned int*)d_in[0], flag);
    cvtx_kernel<<<(NX / 4 + 255) / 256, 256, 0, stream>>>(d_in[0], xc, NX / 4, flag);
    CvtBatch cb;
    cb.src[0] = d_in[3];  cb.dst[0] = w1c;  cb.n[0] = NW1;
    cb.src[1] = d_in[4];  cb.dst[1] = a1sc; cb.n[1] = NA;
    cb.src[2] = d_in[5];  cb.dst[2] = a1dc; cb.n[2] = NA;
    cb.src[3] = d_in[6];  cb.dst[3] = b1c;  cb.n[3] = NB1;
    cb.src[4] = d_in[7];  cb.dst[4] = w2c;  cb.n[4] = NW2;
    cb.src[5] = d_in[8];  cb.dst[5] = a2sc; cb.n[5] = NA2;
    cb.src[6] = d_in[9];  cb.dst[6] = a2dc; cb.n[6] = NA2;
    cb.src[7] = d_in[10]; cb.dst[7] = b2c;  cb.n[7] = NB2;
    int totalSmall = NW1 + NA + NA + NB1 + NW2 + NA2 + NA2 + NB2;
    cvt_batch_kernel<<<(totalSmall + 255) / 256, 256, 0, stream>>>(cb, flag);

    // CSR build
    hipMemsetAsync(deg, 0, (size_t)N * 4, stream);
    hipMemsetAsync(csr, 0, (size_t)ET * 4, stream);
    int gE = (ET + 255) / 256;
    int gN256 = (N + 255) / 256;
    deg_kernel<<<gE, 256, 0, stream>>>(ei, E, N, deg);
    scan_bsum_kernel<<<gN256, 256, 0, stream>>>(deg, bsum, N);
    scan_scan_kernel<<<1, 256, 0, stream>>>(bsum, gN256, rowptr + N);
    scan_write_kernel<<<gN256, 256, 0, stream>>>(deg, bsum, rowptr, cursor, N);
    scatter_kernel<<<gE, 256, 0, stream>>>(ei, E, N, cursor, csr);

    int numM = (N + 127) / 128;
    int gNode = (N + 3) / 4;

    // layer 1
    gemm_tile_kernel<512, 2><<<numM * 2, 256, 0, stream>>>(xc, w1c, h1, N);
    escore_kernel<4><<<gNode, 256, 0, stream>>>(h1, a1sc, a1dc, es, ed, N);
    aggregate_kernel<256, true, false><<<gNode, 256, 0, stream>>>(h1, es, ed, rowptr, csr, b1c,
                                                                  out1, N, ET, flag);
    // layer 2 (h2 reuses h1 buffer)
    unsigned short* h2 = h1;
    gemm_tile_kernel<256, 1><<<numM, 256, 0, stream>>>(out1, w2c, h2, N);
    escore_kernel<2><<<gNode, 256, 0, stream>>>(h2, a2sc, a2dc, es, ed, N);
    aggregate_kernel<128, false, true><<<gNode, 256, 0, stream>>>(h2, es, ed, rowptr, csr, b2c,
                                                                  d_out, N, ET, flag);
}